// Round 3
// baseline (288.541 us; speedup 1.0000x reference)
//
#include <hip/hip_runtime.h>

// Problem constants
#define B_ 2
#define N_ 196608
#define K_ 9
#define F_ 64
#define WROWS 32  // n-rows per wave (1-wave blocks, barrier-free, zero LDS)

typedef __attribute__((ext_vector_type(8))) short short8;
typedef __attribute__((ext_vector_type(4))) unsigned short ushort4v;
typedef __attribute__((ext_vector_type(4))) float f32x4;

__device__ __forceinline__ unsigned short f2bf(float f) {
  unsigned u = __builtin_bit_cast(unsigned, f);
  u = (u + 0x7fffu + ((u >> 16) & 1u)) >> 16;  // RNE
  return (unsigned short)u;
}

// Fused setup kernel.
// Blocks [0, XBLK): x fp32 [B][N][64] -> xb bf16 [N][B][64], thread = one 16B chunk.
// Blocks [XBLK, XBLK+144): W fp32 [9][64][64] (k,f,o) -> wt bf16 [9][64][64] (k,o,f).
#define XCHUNKS (2L * N_ * 16)     // 16B chunks over both planes
#define XBLK ((int)(XCHUNKS / 256))
__global__ __launch_bounds__(256) void cvt_kernel(const float* __restrict__ x,
                                                  unsigned short* __restrict__ xb,
                                                  const float* __restrict__ W,
                                                  unsigned short* __restrict__ wt) {
  if (blockIdx.x < (unsigned)XBLK) {
    const long i = (long)blockIdx.x * 256 + threadIdx.x;  // global 16B-chunk id
    const long pn = (long)N_ * 16;                        // chunks per plane
    const int b = (int)(i >= pn);
    const long ci = i - (long)b * pn;
    const long n = ci >> 4;
    const int qd = (int)(ci & 15);
    const float4 v = *(const float4*)(x + ((size_t)b * N_ + n) * F_ + (size_t)qd * 4);
    ushort4v r;
    r[0] = f2bf(v.x); r[1] = f2bf(v.y); r[2] = f2bf(v.z); r[3] = f2bf(v.w);
    *(ushort4v*)(xb + ((size_t)n * 2 + b) * F_ + qd * 4) = r;
  } else {
    const int i = (blockIdx.x - XBLK) * 256 + threadIdx.x;  // < 9*64*64 = 36864
    const int k = i >> 12;
    const int rem = i & 4095;
    const int o = rem >> 6;
    const int f = rem & 63;
    wt[i] = f2bf(W[(k << 12) + (f << 6) + o]);
  }
}

// Main: ONE 64-lane wave per block, 32 rows, ZERO LDS, ZERO barriers.
// The gather loads straight into MFMA A-fragment registers (lane (q,c) reads
// xb[adj[rt*16+c][k]] at chunk fs*4+q) -- each staged chunk was consumed by exactly
// one lane anyway, so the old LDS round-trip was pure overhead. Ping-pong register
// prefetch (A and Wt one k ahead); compiler emits per-register vmcnt waits, so set
// k+1 stays in flight through set k's MFMAs. Occupancy 8 waves/CU (VGPR-capped).
__global__ __launch_bounds__(64, 2) void nhconv_main(
    const short* __restrict__ xb,    // [N][2][64] bf16 bits, 256 B per n
    const int* __restrict__ adjc,    // [N][9] int32
    const short* __restrict__ wt,    // [9][64][64] bf16 bits, Wt[k][o][f]
    const float* __restrict__ bias,  // [64]
    float* __restrict__ out) {       // [2][N][64] fp32
  const int l = (int)threadIdx.x;
  const int n0 = blockIdx.x * WROWS;
  const int q = l >> 4;  // quad 0..3 (K-group of the A fragment)
  const int c = l & 15;  // A row-in-tile / Wt o-row

  // Per-lane adjacency in registers: rows n0 + rt*16 + c, all 9 neighbors.
  int aj[2][K_];
#pragma unroll
  for (int rt = 0; rt < 2; ++rt) {
    const int* ap = adjc + (size_t)(n0 + rt * 16 + c) * K_;
#pragma unroll
    for (int k = 0; k < K_; ++k) aj[rt][k] = ap[k];
  }

  // A fragments: [parity][p*4 + fs*2 + rt]; Wt fragments: [parity][fs*4 + ct].
  short8 ra[2][8], rw[2][8];
  const short* wbase = wt + q * 8 + (c << 6);

  auto aload = [&](int k, int par) {
#pragma unroll
    for (int p = 0; p < 2; ++p)
#pragma unroll
      for (int fs = 0; fs < 2; ++fs)
#pragma unroll
        for (int rt = 0; rt < 2; ++rt)
          ra[par][p * 4 + fs * 2 + rt] = *(const short8*)(
              xb + ((size_t)(unsigned)aj[rt][k] << 7) + p * 64 + fs * 32 + q * 8);
  };
  auto wload = [&](int k, int par) {
#pragma unroll
    for (int fs = 0; fs < 2; ++fs)
#pragma unroll
      for (int ct = 0; ct < 4; ++ct)
        rw[par][fs * 4 + ct] = *(const short8*)(wbase + (k << 12) + fs * 32 + (ct << 10));
  };

  f32x4 acc[2][2][4];  // [plane][row-tile][ct]
#pragma unroll
  for (int p = 0; p < 2; ++p)
#pragma unroll
    for (int rt = 0; rt < 2; ++rt)
#pragma unroll
      for (int ct = 0; ct < 4; ++ct)
        acc[p][rt][ct] = (f32x4){0.f, 0.f, 0.f, 0.f};

  // Prologue: set 0 in flight.
  aload(0, 0);
  wload(0, 0);

#pragma unroll
  for (int k = 0; k < K_; ++k) {
    if (k + 1 < K_) {  // issue set k+1 before consuming set k
      aload(k + 1, (k + 1) & 1);
      wload(k + 1, (k + 1) & 1);
    }
#pragma unroll
    for (int fs = 0; fs < 2; ++fs)
#pragma unroll
      for (int rt = 0; rt < 2; ++rt)
#pragma unroll
        for (int ct = 0; ct < 4; ++ct) {
          const short8 bfr = rw[k & 1][fs * 4 + ct];
          acc[0][rt][ct] = __builtin_amdgcn_mfma_f32_16x16x32_bf16(
              ra[k & 1][0 + fs * 2 + rt], bfr, acc[0][rt][ct], 0, 0, 0);
          acc[1][rt][ct] = __builtin_amdgcn_mfma_f32_16x16x32_bf16(
              ra[k & 1][4 + fs * 2 + rt], bfr, acc[1][rt][ct], 0, 0, 0);
        }
  }

  // Epilogue: C col = lane&15, row-in-tile = quad*4 + reg; nontemporal stores.
  float bv[4];
#pragma unroll
  for (int ct = 0; ct < 4; ++ct) bv[ct] = bias[ct * 16 + c];

#pragma unroll
  for (int p = 0; p < 2; ++p) {
    const size_t outbase = ((size_t)p * N_ + (size_t)n0) * F_;
#pragma unroll
    for (int rt = 0; rt < 2; ++rt) {
#pragma unroll
      for (int ct = 0; ct < 4; ++ct) {
#pragma unroll
        for (int rr = 0; rr < 4; ++rr) {
          const int row = rt * 16 + q * 4 + rr;
          __builtin_nontemporal_store(acc[p][rt][ct][rr] + bv[ct],
                                      &out[outbase + (size_t)row * F_ + ct * 16 + c]);
        }
      }
    }
  }
}

extern "C" void kernel_launch(void* const* d_in, const int* in_sizes, int n_in,
                              void* d_out, int out_size, void* d_ws, size_t ws_size,
                              hipStream_t stream) {
  const float* x = (const float*)d_in[0];
  const int* adjc = (const int*)d_in[1];
  const float* W = (const float*)d_in[2];
  const float* bias = (const float*)d_in[3];
  float* out = (float*)d_out;

  unsigned short* xb = (unsigned short*)d_ws;  // 50,331,648 B
  unsigned short* wt = (unsigned short*)((char*)d_ws + (size_t)B_ * N_ * F_ * 2);

  cvt_kernel<<<XBLK + 144, 256, 0, stream>>>(x, xb, W, wt);

  nhconv_main<<<N_ / WROWS, 64, 0, stream>>>((const short*)xb, adjc, (const short*)wt,
                                             bias, out);
}

// Round 4
// 279.705 us; speedup vs baseline: 1.0316x; 1.0316x over previous
//
#include <hip/hip_runtime.h>

// Problem constants
#define B_ 2
#define N_ 196608
#define K_ 9
#define F_ 64
#define WROWS 32   // n-rows per wave
#define BROWS 128  // 4 waves per block; zero LDS, barrier used only for alignment

typedef __attribute__((ext_vector_type(8))) short short8;
typedef __attribute__((ext_vector_type(4))) unsigned short ushort4v;
typedef __attribute__((ext_vector_type(4))) float f32x4;

__device__ __forceinline__ unsigned short f2bf(float f) {
  unsigned u = __builtin_bit_cast(unsigned, f);
  u = (u + 0x7fffu + ((u >> 16) & 1u)) >> 16;  // RNE
  return (unsigned short)u;
}

// Fused setup kernel.
// Blocks [0, XBLK): x fp32 [B][N][64] -> xb bf16 [N][B][64], thread = one 16B chunk.
// Blocks [XBLK, XBLK+144): W fp32 [9][64][64] (k,f,o) -> wt bf16 [9][64][64] (k,o,f).
#define XCHUNKS (2L * N_ * 16)  // 16B chunks over both planes
#define XBLK ((int)(XCHUNKS / 256))
__global__ __launch_bounds__(256) void cvt_kernel(const float* __restrict__ x,
                                                  unsigned short* __restrict__ xb,
                                                  const float* __restrict__ W,
                                                  unsigned short* __restrict__ wt) {
  if (blockIdx.x < (unsigned)XBLK) {
    const long i = (long)blockIdx.x * 256 + threadIdx.x;  // global 16B-chunk id
    const long pn = (long)N_ * 16;                        // chunks per plane
    const int b = (int)(i >= pn);
    const long ci = i - (long)b * pn;
    const long n = ci >> 4;
    const int qd = (int)(ci & 15);
    const float4 v = *(const float4*)(x + ((size_t)b * N_ + n) * F_ + (size_t)qd * 4);
    ushort4v r;
    r[0] = f2bf(v.x); r[1] = f2bf(v.y); r[2] = f2bf(v.z); r[3] = f2bf(v.w);
    *(ushort4v*)(xb + ((size_t)n * 2 + b) * F_ + qd * 4) = r;
  } else {
    const int i = (blockIdx.x - XBLK) * 256 + threadIdx.x;  // < 9*64*64 = 36864
    const int k = i >> 12;
    const int rem = i & 4095;
    const int o = rem >> 6;
    const int f = rem & 63;
    wt[i] = f2bf(W[(k << 12) + (f << 6) + o]);
  }
}

// Main: 4-wave blocks, 32 rows/wave, ZERO LDS. Gather loads go straight into MFMA
// A-fragment registers (each staged chunk had exactly one consumer lane). Fixes vs
// round 3: (1) sched_barrier(0) between the prefetch group and the MFMA group stops
// the scheduler from sinking loads into the consume region (round 3's VGPR=84 showed
// the ping-pong was collapsed -> depth-0 pipeline); (2) W redundancy amortized by
// running 4 waves per block time-aligned with a raw s_barrier per k, so the 4 waves'
// identical wt reads (8 KB per k, L1-resident) coalesce in L1: ~3/4 of W requests
// become L1 hits. W single-buffered (L1-hot, loaded at iter top); A ping-ponged one
// k ahead. No cross-wave dataflow -> the barrier aligns, it does not guard.
__global__ __launch_bounds__(256, 2) void nhconv_main(
    const short* __restrict__ xb,    // [N][2][64] bf16 bits, 256 B per n
    const int* __restrict__ adjc,    // [N][9] int32
    const short* __restrict__ wt,    // [9][64][64] bf16 bits, Wt[k][o][f]
    const float* __restrict__ bias,  // [64]
    float* __restrict__ out) {       // [2][N][64] fp32
  const int tid = (int)threadIdx.x;
  const int w = tid >> 6;  // wave 0..3
  const int l = tid & 63;
  const int q = l >> 4;  // quad 0..3 (K-group of the A fragment)
  const int c = l & 15;  // A row-in-tile / Wt o-row
  const int n0 = blockIdx.x * BROWS + w * WROWS;

  // Per-lane adjacency in registers: rows n0 + rt*16 + c, all 9 neighbors.
  int aj[2][K_];
#pragma unroll
  for (int rt = 0; rt < 2; ++rt) {
    const int* ap = adjc + (size_t)(n0 + rt * 16 + c) * K_;
#pragma unroll
    for (int k = 0; k < K_; ++k) aj[rt][k] = ap[k];
  }

  // A fragments: [parity][p*4 + fs*2 + rt]; Wt fragments: [fs*4 + ct].
  short8 ra[2][8], rw[8];
  const short* wbase = wt + q * 8 + (c << 6);

  auto aload = [&](int k, int par) {
#pragma unroll
    for (int p = 0; p < 2; ++p)
#pragma unroll
      for (int fs = 0; fs < 2; ++fs)
#pragma unroll
        for (int rt = 0; rt < 2; ++rt)
          ra[par][p * 4 + fs * 2 + rt] = *(const short8*)(
              xb + ((size_t)(unsigned)aj[rt][k] << 7) + p * 64 + fs * 32 + q * 8);
  };
  auto wload = [&](int k) {
#pragma unroll
    for (int fs = 0; fs < 2; ++fs)
#pragma unroll
      for (int ct = 0; ct < 4; ++ct)
        rw[fs * 4 + ct] = *(const short8*)(wbase + (k << 12) + fs * 32 + (ct << 10));
  };

  f32x4 acc[2][2][4];  // [plane][row-tile][ct]
#pragma unroll
  for (int p = 0; p < 2; ++p)
#pragma unroll
    for (int rt = 0; rt < 2; ++rt)
#pragma unroll
      for (int ct = 0; ct < 4; ++ct)
        acc[p][rt][ct] = (f32x4){0.f, 0.f, 0.f, 0.f};

  // Prologue: A set 0 in flight.
  aload(0, 0);

#pragma unroll
  for (int k = 0; k < K_; ++k) {
    if (k > 0) __builtin_amdgcn_s_barrier();  // align waves -> W reads cluster in L1
    wload(k);                                  // issued BEFORE aload(k+1): the wait
    if (k + 1 < K_) aload(k + 1, (k + 1) & 1); // for rw leaves A(k+1) in flight
    __builtin_amdgcn_sched_barrier(0);         // loads may not sink past this point

#pragma unroll
    for (int fs = 0; fs < 2; ++fs)
#pragma unroll
      for (int rt = 0; rt < 2; ++rt)
#pragma unroll
        for (int ct = 0; ct < 4; ++ct) {
          const short8 bfr = rw[fs * 4 + ct];
          acc[0][rt][ct] = __builtin_amdgcn_mfma_f32_16x16x32_bf16(
              ra[k & 1][0 + fs * 2 + rt], bfr, acc[0][rt][ct], 0, 0, 0);
          acc[1][rt][ct] = __builtin_amdgcn_mfma_f32_16x16x32_bf16(
              ra[k & 1][4 + fs * 2 + rt], bfr, acc[1][rt][ct], 0, 0, 0);
        }
  }

  // Epilogue: C col = lane&15, row-in-tile = quad*4 + reg; nontemporal stores.
  float bv[4];
#pragma unroll
  for (int ct = 0; ct < 4; ++ct) bv[ct] = bias[ct * 16 + c];

#pragma unroll
  for (int p = 0; p < 2; ++p) {
    const size_t outbase = ((size_t)p * N_ + (size_t)n0) * F_;
#pragma unroll
    for (int rt = 0; rt < 2; ++rt) {
#pragma unroll
      for (int ct = 0; ct < 4; ++ct) {
#pragma unroll
        for (int rr = 0; rr < 4; ++rr) {
          const int row = rt * 16 + q * 4 + rr;
          __builtin_nontemporal_store(acc[p][rt][ct][rr] + bv[ct],
                                      &out[outbase + (size_t)row * F_ + ct * 16 + c]);
        }
      }
    }
  }
}

extern "C" void kernel_launch(void* const* d_in, const int* in_sizes, int n_in,
                              void* d_out, int out_size, void* d_ws, size_t ws_size,
                              hipStream_t stream) {
  const float* x = (const float*)d_in[0];
  const int* adjc = (const int*)d_in[1];
  const float* W = (const float*)d_in[2];
  const float* bias = (const float*)d_in[3];
  float* out = (float*)d_out;

  unsigned short* xb = (unsigned short*)d_ws;  // 50,331,648 B
  unsigned short* wt = (unsigned short*)((char*)d_ws + (size_t)B_ * N_ * F_ * 2);

  cvt_kernel<<<XBLK + 144, 256, 0, stream>>>(x, xb, W, wt);

  nhconv_main<<<N_ / BROWS, 256, 0, stream>>>((const short*)xb, adjc, (const short*)wt,
                                              bias, out);
}

// Round 5
// 259.701 us; speedup vs baseline: 1.1111x; 1.0770x over previous
//
#include <hip/hip_runtime.h>

// Problem constants
#define B_ 2
#define N_ 196608
#define K_ 9
#define F_ 64
#define WAVES 8
#define WROWS 32                 // n-rows per wave
#define BROWS (WAVES * WROWS)    // 256 rows per block
#define WT16 (K_ * 64 * 8)       // wt size in 16B chunks = 4608 (72 KB)

typedef __attribute__((ext_vector_type(8))) short short8;
typedef __attribute__((ext_vector_type(4))) unsigned short ushort4v;
typedef __attribute__((ext_vector_type(4))) float f32x4;

__device__ __forceinline__ unsigned short f2bf(float f) {
  unsigned u = __builtin_bit_cast(unsigned, f);
  u = (u + 0x7fffu + ((u >> 16) & 1u)) >> 16;  // RNE
  return (unsigned short)u;
}

// Fused setup kernel.
// Blocks [0, XBLK): x fp32 [B][N][64] -> xb bf16 [N][B][64], thread = one 16B chunk.
// Blocks [XBLK, XBLK+144): W fp32 [9][64][64] (k,f,o) -> wt bf16 [9][64][64] (k,o,f).
#define XCHUNKS (2L * N_ * 16)  // 16B chunks over both planes
#define XBLK ((int)(XCHUNKS / 256))
__global__ __launch_bounds__(256) void cvt_kernel(const float* __restrict__ x,
                                                  unsigned short* __restrict__ xb,
                                                  const float* __restrict__ W,
                                                  unsigned short* __restrict__ wt) {
  if (blockIdx.x < (unsigned)XBLK) {
    const long i = (long)blockIdx.x * 256 + threadIdx.x;  // global 16B-chunk id
    const long pn = (long)N_ * 16;                        // chunks per plane
    const int b = (int)(i >= pn);
    const long ci = i - (long)b * pn;
    const long n = ci >> 4;
    const int qd = (int)(ci & 15);
    const float4 v = *(const float4*)(x + ((size_t)b * N_ + n) * F_ + (size_t)qd * 4);
    ushort4v r;
    r[0] = f2bf(v.x); r[1] = f2bf(v.y); r[2] = f2bf(v.z); r[3] = f2bf(v.w);
    *(ushort4v*)(xb + ((size_t)n * 2 + b) * F_ + qd * 4) = r;
  } else {
    const int i = (blockIdx.x - XBLK) * 256 + threadIdx.x;  // < 9*64*64 = 36864
    const int k = i >> 12;
    const int rem = i & 4095;
    const int o = rem >> 6;
    const int f = rem & 63;
    wt[i] = f2bf(W[(k << 12) + (f << 6) + o]);
  }
}

// Main: 8-wave blocks, 32 rows/wave, 768 blocks. Bound by global 64B-granule request
// rate (~125 G/s across rounds 2-4), so this round removes W from the fabric: wt
// (72 KB) is staged ONCE per block into LDS (chunk-XOR swizzle at ds_write time ->
// per-iter ds_read_b128 B-fragment reads are uniform 8/bank). W granules drop
// 7.08M -> 0.88M. A gathers stay direct-to-register (zero round-trip), 3-set
// rotating prefetch (issue k+2 while consuming k) guarded by sched_barrier(0).
// Adjacency staged via LDS so any remat is a ds_read, never a global load (R4 bug).
// k-loop has ZERO barriers: LDS is read-only after the single staging barrier.
__global__ __launch_bounds__(512, 2) void nhconv_main(
    const short* __restrict__ xb,    // [N][2][64] bf16 bits, 256 B per n
    const int* __restrict__ adjc,    // [N][9] int32
    const short* __restrict__ wt,    // [9][64][64] bf16 bits, Wt[k][o][f]
    const float* __restrict__ bias,  // [64]
    float* __restrict__ out) {       // [2][N][64] fp32
  __shared__ __align__(16) short lds_wt[WT16 * 8];  // 73728 B, swizzled chunks
  __shared__ int s_adj[BROWS * K_];                 // 9216 B

  const int tid = (int)threadIdx.x;
  const int w = tid >> 6;  // wave 0..7
  const int l = tid & 63;
  const int q = l >> 4;  // quad 0..3 (K-group of the A fragment)
  const int c = l & 15;  // A row-in-tile / Wt o-row
  const int n0 = blockIdx.x * BROWS + w * WROWS;

  // ---- Stage W into LDS with chunk-XOR swizzle. Global read coalesced (16B/lane),
  // ds_write_b128 uniform 8 accesses/bank. Logical [k][o][ch] -> LDS [k][o][ch^(o&7)].
  {
    const short8* wt16 = (const short8*)wt;
    short8* lwt16 = (short8*)lds_wt;
    for (int g = tid; g < WT16; g += 512) {
      const int o = (g >> 3) & 63;
      const int ch = g & 7;
      lwt16[(g & ~7) | (ch ^ (o & 7))] = wt16[g];
    }
  }
  // ---- Stage adjacency rows for this block.
  for (int i = tid; i < BROWS * K_; i += 512)
    s_adj[i] = __builtin_nontemporal_load(adjc + (size_t)blockIdx.x * BROWS * K_ + i);
  __syncthreads();  // the only barrier; LDS is read-only below

  // Per-lane adjacency into registers (remat, if any, is a cheap ds_read).
  int aj[2][K_];
#pragma unroll
  for (int rt = 0; rt < 2; ++rt)
#pragma unroll
    for (int k = 0; k < K_; ++k)
      aj[rt][k] = s_adj[(w * WROWS + rt * 16 + c) * K_ + k];

  // A fragments: 3 rotating sets [set][p*4 + fs*2 + rt] (depth-2 prefetch).
  short8 ra[3][8];
  auto aload = [&](int k, int set) {
#pragma unroll
    for (int p = 0; p < 2; ++p)
#pragma unroll
      for (int fs = 0; fs < 2; ++fs)
#pragma unroll
        for (int rt = 0; rt < 2; ++rt)
          ra[set][p * 4 + fs * 2 + rt] = *(const short8*)(
              xb + ((size_t)(unsigned)aj[rt][k] << 7) + p * 64 + fs * 32 + q * 8);
  };

  // W fragment read from LDS (swizzled): lane (q,c) wants [k][o=ct*16+c][ch=fs*4+q].
  const short8* lwt16 = (const short8*)lds_wt;
  f32x4 acc[2][2][4];  // [plane][row-tile][ct]
#pragma unroll
  for (int p = 0; p < 2; ++p)
#pragma unroll
    for (int rt = 0; rt < 2; ++rt)
#pragma unroll
      for (int ct = 0; ct < 4; ++ct)
        acc[p][rt][ct] = (f32x4){0.f, 0.f, 0.f, 0.f};

  // Prologue: sets 0 and 1 in flight.
  aload(0, 0);
  aload(1, 1);

#pragma unroll
  for (int k = 0; k < K_; ++k) {
    if (k + 2 < K_) aload(k + 2, (k + 2) % 3);  // keep ~32 gathers in flight
    short8 rw[8];
#pragma unroll
    for (int fs = 0; fs < 2; ++fs)
#pragma unroll
      for (int ct = 0; ct < 4; ++ct)
        rw[fs * 4 + ct] =
            lwt16[k * 512 + (ct * 16 + c) * 8 + ((fs * 4 + q) ^ (c & 7))];
    __builtin_amdgcn_sched_barrier(0);  // prefetch may not sink into the MFMA region

#pragma unroll
    for (int fs = 0; fs < 2; ++fs)
#pragma unroll
      for (int rt = 0; rt < 2; ++rt)
#pragma unroll
        for (int ct = 0; ct < 4; ++ct) {
          const short8 bfr = rw[fs * 4 + ct];
          acc[0][rt][ct] = __builtin_amdgcn_mfma_f32_16x16x32_bf16(
              ra[k % 3][0 + fs * 2 + rt], bfr, acc[0][rt][ct], 0, 0, 0);
          acc[1][rt][ct] = __builtin_amdgcn_mfma_f32_16x16x32_bf16(
              ra[k % 3][4 + fs * 2 + rt], bfr, acc[1][rt][ct], 0, 0, 0);
        }
  }

  // Epilogue: C col = lane&15, row-in-tile = quad*4 + reg; nontemporal stores.
  float bv[4];
#pragma unroll
  for (int ct = 0; ct < 4; ++ct) bv[ct] = bias[ct * 16 + c];

#pragma unroll
  for (int p = 0; p < 2; ++p) {
    const size_t outbase = ((size_t)p * N_ + (size_t)n0) * F_;
#pragma unroll
    for (int rt = 0; rt < 2; ++rt) {
#pragma unroll
      for (int ct = 0; ct < 4; ++ct) {
#pragma unroll
        for (int rr = 0; rr < 4; ++rr) {
          const int row = rt * 16 + q * 4 + rr;
          __builtin_nontemporal_store(acc[p][rt][ct][rr] + bv[ct],
                                      &out[outbase + (size_t)row * F_ + ct * 16 + c]);
        }
      }
    }
  }
}

extern "C" void kernel_launch(void* const* d_in, const int* in_sizes, int n_in,
                              void* d_out, int out_size, void* d_ws, size_t ws_size,
                              hipStream_t stream) {
  const float* x = (const float*)d_in[0];
  const int* adjc = (const int*)d_in[1];
  const float* W = (const float*)d_in[2];
  const float* bias = (const float*)d_in[3];
  float* out = (float*)d_out;

  unsigned short* xb = (unsigned short*)d_ws;  // 50,331,648 B
  unsigned short* wt = (unsigned short*)((char*)d_ws + (size_t)B_ * N_ * F_ * 2);

  cvt_kernel<<<XBLK + 144, 256, 0, stream>>>(x, xb, W, wt);

  nhconv_main<<<N_ / BROWS, 512, 0, stream>>>((const short*)xb, adjc, (const short*)wt,
                                              bias, out);
}